// Round 2
// baseline (65871.405 us; speedup 1.0000x reference)
//
#include <hip/hip_runtime.h>

#define NTHREADS 1024
#define NB 256
#define TT 64
#define NV 19

// LDS float-index offsets (all 16B aligned)
#define SM_OFF   0      // 368
#define H0_OFF   368    // 2432
#define H1_OFF   2800   // 2432
#define CUR_OFF  5232   // 1904
#define XS_OFF   7136   // 4864
#define M1_OFF   12000  // 4864
#define M2_OFF   16864  // 4864
#define GB_OFF   21728  // 4864
#define CB_OFF   26592  // 2432
#define BGE0_OFF 29024  // 256
#define BCE0_OFF 29280  // 128
#define BGE1_OFF 29408  // 256
#define BCE1_OFF 29664  // 128
#define BGD0_OFF 29792  // 256
#define BCD0_OFF 30048  // 128
#define BGD1_OFF 30176  // 256
#define BCD1_OFF 30432  // 128
#define BP_OFF   30560  // 128
#define LDS_FLOATS 30688

__device__ __forceinline__ void lds_fadd(float* p, float v) {
    unsafeAtomicAdd(p, v);   // native ds_add_f32 on LDS — never a CAS loop
}

// ---- diffusion: dst = S @ src  (or 2*(S@src) - sub). rows 19, cols 256.
// thread slot = (row-pair p, quad c4): rows p and p+10 share the src reads.
__device__ __forceinline__ void diffuse(const float* Sm, const float* src, float* dst,
                                        const float* sub, int tid)
{
    if (tid >= 640) return;
    const int p  = tid >> 6;          // 0..9, wave-uniform
    const int c4 = (tid & 63) << 2;
    const bool two = (p < 9);
    float4 a0 = {0.f,0.f,0.f,0.f};
    float4 a1 = {0.f,0.f,0.f,0.f};
#pragma unroll 1
    for (int m = 0; m < 19; ++m) {
        const float4 x4 = *(const float4*)(src + (m << 8) + c4);
        const float s0 = Sm[p * 19 + m];
        const float s1 = two ? Sm[(p + 10) * 19 + m] : 0.f;
        a0.x += s0 * x4.x; a0.y += s0 * x4.y; a0.z += s0 * x4.z; a0.w += s0 * x4.w;
        a1.x += s1 * x4.x; a1.y += s1 * x4.y; a1.z += s1 * x4.z; a1.w += s1 * x4.w;
    }
    if (sub) {
        const float4 u0 = *(const float4*)(sub + (p << 8) + c4);
        a0.x = 2.f*a0.x - u0.x; a0.y = 2.f*a0.y - u0.y;
        a0.z = 2.f*a0.z - u0.z; a0.w = 2.f*a0.w - u0.w;
        if (two) {
            const float4 u1 = *(const float4*)(sub + ((p+10) << 8) + c4);
            a1.x = 2.f*a1.x - u1.x; a1.y = 2.f*a1.y - u1.y;
            a1.z = 2.f*a1.z - u1.z; a1.w = 2.f*a1.w - u1.w;
        }
    }
    *(float4*)(dst + (p << 8) + c4) = a0;
    if (two) *(float4*)(dst + ((p+10) << 8) + c4) = a1;
}

// ---- gates GEMM: gb(19x256) += stackedX(19 x 3D) @ Wg(3D x 256)
// wave = K-chunk of 16 d-rows; lane owns cols jt*64+lane (JT=4).
// X quad read is wave-uniform -> broadcast ds_read_b128; 1 read feeds 16 FMAs/lane.
__device__ __forceinline__ void gemm_gates(const float* xs, float* gb,
                                           const float* __restrict__ W, int D, int tid)
{
    const int wave = tid >> 6, lane = tid & 63;
    float acc[19][4];
#pragma unroll
    for (int n = 0; n < 19; ++n)
#pragma unroll
        for (int jt = 0; jt < 4; ++jt) acc[n][jt] = 0.f;
    const int dch = wave << 4;
#pragma unroll 1
    for (int q = 0; q < 4; ++q) {
        const int d0 = dch + (q << 2);
        if (d0 >= D) break;                       // wave-uniform (layer0 pad)
#pragma unroll 1
        for (int kp = 0; kp < 3; ++kp) {
            const float* Xm = xs + kp * 4864;
            float w[4][4];
#pragma unroll
            for (int r = 0; r < 4; ++r) {
                const float* Wr = W + (size_t)(3 * (d0 + r) + kp) * 256 + lane;
#pragma unroll
                for (int jt = 0; jt < 4; ++jt) w[r][jt] = Wr[jt * 64];
            }
#pragma unroll
            for (int n = 0; n < 19; ++n) {
                const float4 x4 = *(const float4*)(Xm + (n << 8) + d0);
#pragma unroll
                for (int jt = 0; jt < 4; ++jt) {
                    acc[n][jt] += x4.x * w[0][jt];
                    acc[n][jt] += x4.y * w[1][jt];
                    acc[n][jt] += x4.z * w[2][jt];
                    acc[n][jt] += x4.w * w[3][jt];
                }
            }
        }
    }
#pragma unroll
    for (int n = 0; n < 19; ++n)
#pragma unroll
        for (int jt = 0; jt < 4; ++jt)
            lds_fadd(gb + (n << 8) + jt * 64 + lane, acc[n][jt]);
}

// ---- candidate GEMM: cb(19x128) += stackedX(19 x 3D) @ Wc(3D x 128)
// half-wave teams: jg=lane&31, chunk=(wave<<1)|(lane>>5) -> 32 chunks x 8 d-rows; JT=4.
__device__ __forceinline__ void gemm_cand(const float* xs, float* cb,
                                          const float* __restrict__ W, int D, int tid)
{
    const int wave = tid >> 6, lane = tid & 63, jg = lane & 31;
    const int dch = (((wave << 1) | (lane >> 5)) << 3);
    float acc[19][4];
#pragma unroll
    for (int n = 0; n < 19; ++n)
#pragma unroll
        for (int jt = 0; jt < 4; ++jt) acc[n][jt] = 0.f;
#pragma unroll 1
    for (int q = 0; q < 2; ++q) {
        const int d0 = dch + (q << 2);
        if (d0 < D) {                             // half-wave divergent, short
#pragma unroll 1
            for (int kp = 0; kp < 3; ++kp) {
                const float* Xm = xs + kp * 4864;
                float w[4][4];
#pragma unroll
                for (int r = 0; r < 4; ++r) {
                    const float* Wr = W + (size_t)(3 * (d0 + r) + kp) * 128 + jg;
#pragma unroll
                    for (int jt = 0; jt < 4; ++jt) w[r][jt] = Wr[jt * 32];
                }
#pragma unroll
                for (int n = 0; n < 19; ++n) {
                    const float4 x4 = *(const float4*)(Xm + (n << 8) + d0);
#pragma unroll
                    for (int jt = 0; jt < 4; ++jt) {
                        acc[n][jt] += x4.x * w[0][jt];
                        acc[n][jt] += x4.y * w[1][jt];
                        acc[n][jt] += x4.z * w[2][jt];
                        acc[n][jt] += x4.w * w[3][jt];
                    }
                }
            }
        }
    }
#pragma unroll
    for (int n = 0; n < 19; ++n)
#pragma unroll
        for (int jt = 0; jt < 4; ++jt)
            lds_fadd(cb + (n << 7) + jt * 32 + jg, acc[n][jt]);
}

// ---- projection: cb(19x128-stride, 100 cols) += h1(19x128) @ Wp(128x100)
__device__ __forceinline__ void gemm_proj(const float* h1, float* cb,
                                          const float* __restrict__ Wp, int tid)
{
    const int wave = tid >> 6, lane = tid & 63, jg = lane & 31;
    const int d0 = (((wave << 1) | (lane >> 5)) << 2);   // 32 chunks x 4 rows
    float acc[19][4];
#pragma unroll
    for (int n = 0; n < 19; ++n)
#pragma unroll
        for (int jt = 0; jt < 4; ++jt) acc[n][jt] = 0.f;
    float w[4][4];
#pragma unroll
    for (int r = 0; r < 4; ++r)
#pragma unroll
        for (int jt = 0; jt < 4; ++jt) {
            const int j = jt * 32 + jg;
            w[r][jt] = (j < 100) ? Wp[(size_t)(d0 + r) * 100 + j] : 0.f;
        }
#pragma unroll
    for (int n = 0; n < 19; ++n) {
        const float4 x4 = *(const float4*)(h1 + (n << 7) + d0);
#pragma unroll
        for (int jt = 0; jt < 4; ++jt) {
            acc[n][jt] += x4.x * w[0][jt];
            acc[n][jt] += x4.y * w[1][jt];
            acc[n][jt] += x4.z * w[2][jt];
            acc[n][jt] += x4.w * w[3][jt];
        }
    }
#pragma unroll
    for (int n = 0; n < 19; ++n)
#pragma unroll
        for (int jt = 0; jt < 4; ++jt) {
            const int j = jt * 32 + jg;
            if (j < 100) lds_fadd(cb + (n << 7) + j, acc[n][jt]);
        }
}

// ---- one DCGRU cell: h <- u*h + (1-u)*tanh(dconv(x, r*h))
__device__ __forceinline__ void cell(
    int Dx, const float* x, float* h,
    const float* __restrict__ Wg, const float* bgL,
    const float* __restrict__ Wc, const float* bcL,
    const float* Sm, float* xs, float* m1, float* m2, float* gb, float* cb, int tid)
{
    const int D = Dx + 128;
    for (int i = tid; i < NV * 256; i += NTHREADS) {
        const int n = i >> 8, d = i & 255;
        float v = 0.f;
        if (d < Dx) v = x[n * Dx + d];
        else if (d < D) v = h[(n << 7) + (d - Dx)];
        xs[i] = v;
        gb[i] = bgL[d];
    }
    __syncthreads();
    diffuse(Sm, xs, m1, nullptr, tid);
    __syncthreads();
    diffuse(Sm, m1, m2, xs, tid);
    __syncthreads();
    gemm_gates(xs, gb, Wg, D, tid);
    __syncthreads();
    for (int i = tid; i < NV * 256; i += NTHREADS) {
        const int n = i >> 8, j = i & 255;
        const float sg = 1.f / (1.f + __expf(-gb[i]));
        gb[i] = sg;
        if (j < 128) {
            xs[(n << 8) + Dx + j] = sg * h[(n << 7) + j];
            cb[(n << 7) + j] = bcL[j];
        }
    }
    __syncthreads();
    diffuse(Sm, xs, m1, nullptr, tid);
    __syncthreads();
    diffuse(Sm, m1, m2, xs, tid);
    __syncthreads();
    gemm_cand(xs, cb, Wc, D, tid);
    __syncthreads();
    for (int i = tid; i < NV * 128; i += NTHREADS) {
        const int n = i >> 7, j = i & 127;
        const float u = gb[(n << 8) + 128 + j];
        const float e = __expf(-2.f * cb[i]);
        const float cv = (1.f - e) / (1.f + e);
        h[i] = u * h[i] + (1.f - u) * cv;
    }
    __syncthreads();
}

__global__ __launch_bounds__(NTHREADS) void dcrnn_kernel(
    const float* __restrict__ enc, const float* __restrict__ sup,
    const float* e0Wg, const float* e0bg, const float* e0Wc, const float* e0bc,
    const float* e1Wg, const float* e1bg, const float* e1Wc, const float* e1bc,
    const float* d0Wg, const float* d0bg, const float* d0Wc, const float* d0bc,
    const float* d1Wg, const float* d1bg, const float* d1Wc, const float* d1bc,
    const float* Wp, const float* bp, float* __restrict__ out)
{
    __shared__ __align__(16) float lds[LDS_FLOATS];
    float* Sm  = lds + SM_OFF;
    float* h0  = lds + H0_OFF;
    float* h1  = lds + H1_OFF;
    float* cur = lds + CUR_OFF;
    float* xs  = lds + XS_OFF;
    float* m1  = lds + M1_OFF;
    float* m2  = lds + M2_OFF;
    float* gb  = lds + GB_OFF;
    float* cb  = lds + CB_OFF;

    const int tid = threadIdx.x;
    const int b = blockIdx.x;

    for (int i = tid; i < 361; i += NTHREADS) Sm[i] = sup[i];
    for (int i = tid; i < 2432; i += NTHREADS) { h0[i] = 0.f; h1[i] = 0.f; }
    for (int i = tid; i < 1900; i += NTHREADS) cur[i] = 0.f;
    if (tid < 256) {
        lds[BGE0_OFF + tid] = e0bg[tid];
        lds[BGE1_OFF + tid] = e1bg[tid];
        lds[BGD0_OFF + tid] = d0bg[tid];
        lds[BGD1_OFF + tid] = d1bg[tid];
        if (tid < 128) {
            lds[BCE0_OFF + tid] = e0bc[tid];
            lds[BCE1_OFF + tid] = e1bc[tid];
            lds[BCD0_OFF + tid] = d0bc[tid];
            lds[BCD1_OFF + tid] = d1bc[tid];
            lds[BP_OFF + tid] = (tid < 100) ? bp[tid] : 0.f;
        }
    }
    __syncthreads();

    // encoder: two stacked DCGRU layers per timestep
    for (int t = 0; t < TT; ++t) {
        const float* xg = enc + ((size_t)b * TT + t) * (NV * 100);
        cell(100, xg, h0, e0Wg, lds + BGE0_OFF, e0Wc, lds + BCE0_OFF, Sm, xs, m1, m2, gb, cb, tid);
        cell(128, h0, h1, e1Wg, lds + BGE1_OFF, e1Wc, lds + BCE1_OFF, Sm, xs, m1, m2, gb, cb, tid);
    }
    // decoder: autoregressive, feedback through LDS `cur`
    for (int t = 0; t < TT; ++t) {
        cell(100, cur, h0, d0Wg, lds + BGD0_OFF, d0Wc, lds + BCD0_OFF, Sm, xs, m1, m2, gb, cb, tid);
        cell(128, h0, h1, d1Wg, lds + BGD1_OFF, d1Wc, lds + BCD1_OFF, Sm, xs, m1, m2, gb, cb, tid);
        for (int i = tid; i < NV * 128; i += NTHREADS) cb[i] = lds[BP_OFF + (i & 127)];
        __syncthreads();
        gemm_proj(h1, cb, Wp, tid);
        __syncthreads();
        float* po = out + ((size_t)b * TT + t) * (NV * 100);
        for (int i = tid; i < NV * 100; i += NTHREADS) {
            const int n = i / 100;
            const int o = i - n * 100;
            const float v = cb[(n << 7) + o];
            po[i] = v;
            cur[i] = v;
        }
        __syncthreads();
    }
}

extern "C" void kernel_launch(void* const* d_in, const int* in_sizes, int n_in,
                              void* d_out, int out_size, void* d_ws, size_t ws_size,
                              hipStream_t stream)
{
    const float* enc  = (const float*)d_in[0];
    // d_in[1] = decoder_inputs: unused by reference (autoregressive feedback)
    const float* sup  = (const float*)d_in[2];
    const float* e0Wg = (const float*)d_in[3];
    const float* e0bg = (const float*)d_in[4];
    const float* e0Wc = (const float*)d_in[5];
    const float* e0bc = (const float*)d_in[6];
    const float* e1Wg = (const float*)d_in[7];
    const float* e1bg = (const float*)d_in[8];
    const float* e1Wc = (const float*)d_in[9];
    const float* e1bc = (const float*)d_in[10];
    const float* d0Wg = (const float*)d_in[11];
    const float* d0bg = (const float*)d_in[12];
    const float* d0Wc = (const float*)d_in[13];
    const float* d0bc = (const float*)d_in[14];
    const float* d1Wg = (const float*)d_in[15];
    const float* d1bg = (const float*)d_in[16];
    const float* d1Wc = (const float*)d_in[17];
    const float* d1bc = (const float*)d_in[18];
    const float* Wp   = (const float*)d_in[19];
    const float* bp   = (const float*)d_in[20];

    dcrnn_kernel<<<dim3(NB), dim3(NTHREADS), 0, stream>>>(
        enc, sup,
        e0Wg, e0bg, e0Wc, e0bc, e1Wg, e1bg, e1Wc, e1bc,
        d0Wg, d0bg, d0Wc, d0bc, d1Wg, d1bg, d1Wc, d1bc,
        Wp, bp, (float*)d_out);
}